// Round 4
// baseline (187.064 us; speedup 1.0000x reference)
//
#include <hip/hip_runtime.h>
#include <hip/hip_bf16.h>

#define CELLS 27
#define CIN   32
#define FOUT  64
#define M_OUT 150000
#define N_INP 150000
#define ZROW  N_INP                       /* zero feature row */
#define PPW   32                          /* points per pair */
#define PAIRS ((M_OUT + PPW - 1) / PPW)   /* 4688 */
#define NBLK  ((PAIRS + 1) / 2)           /* 2344: 2 pairs (4 waves) per block */
#define WT_ELEMS (CELLS * CIN * FOUT)     /* 55296 */
#define WT_BYTES (WT_ELEMS * 2)
#define FB_ROWS  (N_INP + 1)
#define FB_BYTES (FB_ROWS * CIN * 2)

typedef __attribute__((ext_vector_type(4))) float f32x4;
typedef __attribute__((ext_vector_type(8))) short bf16x8;

__device__ __forceinline__ short f2bf(float x) {
    union { __hip_bfloat16 h; short s; } u;
    u.h = __float2bfloat16(x);
    return u.s;
}

// Fused prep: fb[i][c] = bf16(feat[i][c]*imp[i]) (+ zero row ZROW), and
// Wt[cell][fout][cin] = bf16(W[cell][cin][fout]).
__global__ __launch_bounds__(256) void prep_kernel(const float* __restrict__ W,
                                                   const float* __restrict__ feat,
                                                   const float* __restrict__ imp,
                                                   unsigned short* __restrict__ Wt,
                                                   unsigned short* __restrict__ fb) {
    int t = blockIdx.x * 256 + threadIdx.x;
    if (t < FB_ROWS * 4) {
        int i = t >> 2, c = t & 3;
        bf16x8 o = {0, 0, 0, 0, 0, 0, 0, 0};
        if (i < N_INP) {
            float w = imp[i];
            const float* fp = feat + (size_t)i * CIN + c * 8;
            f32x4 f0 = *(const f32x4*)fp;
            f32x4 f1 = *(const f32x4*)(fp + 4);
            o[0] = f2bf(f0.x * w); o[1] = f2bf(f0.y * w);
            o[2] = f2bf(f0.z * w); o[3] = f2bf(f0.w * w);
            o[4] = f2bf(f1.x * w); o[5] = f2bf(f1.y * w);
            o[6] = f2bf(f1.z * w); o[7] = f2bf(f1.w * w);
        }
        *(bf16x8*)(fb + (size_t)i * CIN + c * 8) = o;
    } else {
        int u = t - FB_ROWS * 4;
        if (u < WT_ELEMS) {
            int cell = u >> 11;
            int rem  = u & 2047;
            int cin  = rem >> 6;
            int fout = rem & 63;
            Wt[cell * 2048 + fout * 32 + cin] = (unsigned short)f2bf(W[u]);
        }
    }
}

#define CELL_OF(k) (((k) % 3) * 9 + (((k) / 3) % 3) * 3 + ((k) / 9))

// Wave pair per 32 points: wave(fhalf=0) -> fout 0..31, wave(fhalf=1) -> fout 32..63.
__global__ __launch_bounds__(256, 8) void conv_fsplit_kernel(
        const float* __restrict__ opos,
        const float* __restrict__ ipos,
        const int*   __restrict__ nbr,
        const unsigned short* __restrict__ Wt,
        const unsigned short* __restrict__ fb,
        const float* __restrict__ bias,
        float* __restrict__ out) {
    __shared__ int s_idx[2][PPW][28];   // [pair-slot][point][cell], pad 27->28
    __shared__ int s_vox[2][PPW];

    const int wid   = threadIdx.x >> 6;   // 0..3
    const int lane  = threadIdx.x & 63;
    const int pslot = wid >> 1;           // pair slot within block
    const int fhalf = wid & 1;            // which fout half this wave owns
    const int pair  = blockIdx.x * 2 + pslot;
    const int m0    = pair * PPW;

    const int vx0 = (int)ipos[0];
    const int vy0 = (int)ipos[1];
    const int vz0 = (int)ipos[2];

    if (fhalf == 0 && lane < PPW) {
        int m = m0 + lane;
        int vp = -1;
        if (m < M_OUT) {
            vp = ((int)opos[m * 3 + 0] + 1) |
                 (((int)opos[m * 3 + 1] + 1) << 8) |
                 (((int)opos[m * 3 + 2] + 1) << 16);
        }
        s_vox[pslot][lane] = vp;
    }
    __syncthreads();

    // stage 32x27 idx entries with the pair's 128 threads; invalid -> ZROW
#pragma unroll
    for (int it = 0; it < 7; ++it) {
        int e = it * 128 + fhalf * 64 + lane;
        if (e < CELLS * PPW) {
            int p = e / CELLS;
            int k = e - p * CELLS;
            int m = m0 + p;
            int id = (m < M_OUT) ? nbr[m * CELLS + k] : 0;
            int ox = k / 9, oy = (k / 3) % 3, oz = k % 3;   // off+1 in 0..2
            int tgt = (vx0 - ox + 2) | ((vy0 - oy + 2) << 8) | ((vz0 - oz + 2) << 16);
            bool valid = (id != 0) | (s_vox[pslot][p] == tgt);
            s_idx[pslot][p][k] = valid ? id : ZROW;
        }
    }
    __syncthreads();

    const int g = lane >> 4;    // cin group of 8 (MFMA K-slice)
    const int r = lane & 15;    // A row within 16 / B fout within 16-tile

    const unsigned short* fbg = fb + g * 8;
    const unsigned short* wb0 = Wt + (fhalf * 32 + r) * CIN + g * 8;
    const int* idxr0 = &s_idx[pslot][r][0];
    const int* idxr1 = &s_idx[pslot][16 + r][0];

    f32x4 acc[4];
#pragma unroll
    for (int i = 0; i < 4; ++i) acc[i] = (f32x4){0.f, 0.f, 0.f, 0.f};

#pragma unroll
    for (int k = 0; k < CELLS; ++k) {
        const int cell = CELL_OF(k);
        int i0 = idxr0[k];
        int i1 = idxr1[k];
        bf16x8 a0 = *(const bf16x8*)(fbg + (size_t)i0 * CIN);
        bf16x8 a1 = *(const bf16x8*)(fbg + (size_t)i1 * CIN);
        const unsigned short* wb = wb0 + cell * (CIN * FOUT);
        bf16x8 b0 = *(const bf16x8*)(wb);
        bf16x8 b1 = *(const bf16x8*)(wb + 16 * CIN);
        acc[0] = __builtin_amdgcn_mfma_f32_16x16x32_bf16(a0, b0, acc[0], 0, 0, 0);
        acc[1] = __builtin_amdgcn_mfma_f32_16x16x32_bf16(a0, b1, acc[1], 0, 0, 0);
        acc[2] = __builtin_amdgcn_mfma_f32_16x16x32_bf16(a1, b0, acc[2], 0, 0, 0);
        acc[3] = __builtin_amdgcn_mfma_f32_16x16x32_bf16(a1, b1, acc[3], 0, 0, 0);
    }

    // D layout: col = lane&15 (fout within tile), row = (lane>>4)*4 + j (point)
    float bb0 = bias[fhalf * 32 + r];
    float bb1 = bias[fhalf * 32 + 16 + r];
#pragma unroll
    for (int frag = 0; frag < 2; ++frag) {
        int base = m0 + frag * 16 + 4 * g;
#pragma unroll
        for (int j = 0; j < 4; ++j) {
            int m = base + j;
            if (m < M_OUT) {
                float* op = out + (size_t)m * FOUT + fhalf * 32 + r;
                op[0]  = acc[frag * 2 + 0][j] + bb0;
                op[16] = acc[frag * 2 + 1][j] + bb1;
            }
        }
    }
}

extern "C" void kernel_launch(void* const* d_in, const int* in_sizes, int n_in,
                              void* d_out, int out_size, void* d_ws, size_t ws_size,
                              hipStream_t stream) {
    const float* feat = (const float*)d_in[0];
    const float* ipos = (const float*)d_in[1];
    const float* opos = (const float*)d_in[2];
    const float* imp  = (const float*)d_in[4];
    const float* W    = (const float*)d_in[5];
    const float* bias = (const float*)d_in[6];
    const int*   nbr  = (const int*)d_in[7];
    unsigned short* Wt = (unsigned short*)d_ws;
    unsigned short* fb = (unsigned short*)((char*)d_ws + WT_BYTES);
    float* out = (float*)d_out;

    int prep_threads = FB_ROWS * 4 + WT_ELEMS;
    hipLaunchKernelGGL(prep_kernel, dim3((prep_threads + 255) / 256), dim3(256),
                       0, stream, W, feat, imp, Wt, fb);
    hipLaunchKernelGGL(conv_fsplit_kernel, dim3(NBLK), dim3(256), 0, stream,
                       opos, ipos, nbr, Wt, fb, bias, out);
}

// Round 5
// 158.540 us; speedup vs baseline: 1.1799x; 1.1799x over previous
//
#include <hip/hip_runtime.h>
#include <hip/hip_bf16.h>

#define CELLS 27
#define CIN   32
#define FOUT  64
#define M_OUT 150000
#define N_INP 150000
#define ZROW  N_INP                        /* zero feature row */
#define PPG   64                           /* points per group (block) */
#define GROUPS ((M_OUT + PPG - 1) / PPG)   /* 2344 */
#define WT2_SHORTS (CELLS * 4 * 64 * 8)    /* 55296 */
#define WT2_BYTES  (WT2_SHORTS * 2)
#define FB_ROWS  (N_INP + 1)
#define FB_BYTES (FB_ROWS * CIN * 2)

typedef __attribute__((ext_vector_type(4))) float f32x4;
typedef __attribute__((ext_vector_type(8))) short bf16x8;

__device__ __forceinline__ short f2bf(float x) {
    union { __hip_bfloat16 h; short s; } u;
    u.h = __float2bfloat16(x);
    return u.s;
}

#define CELL_OF(k) (((k) % 3) * 9 + (((k) / 3) % 3) * 3 + ((k) / 9))

// Fused prep:
//  fb[i][c] = bf16(feat[i][c]*imp[i]) (+ zero row ZROW)
//  Wt2 fragment-major: short offset (cell*4+tt)*512 + lane*8 holds B-fragment
//  for (fout = tt*16 + (lane&15), cin = (lane>>4)*8 .. +8)
__global__ __launch_bounds__(256) void prep_kernel(const float* __restrict__ W,
                                                   const float* __restrict__ feat,
                                                   const float* __restrict__ imp,
                                                   unsigned short* __restrict__ Wt2,
                                                   unsigned short* __restrict__ fb) {
    int t = blockIdx.x * 256 + threadIdx.x;
    if (t < FB_ROWS * 4) {
        int i = t >> 2, c = t & 3;
        bf16x8 o = {0, 0, 0, 0, 0, 0, 0, 0};
        if (i < N_INP) {
            float w = imp[i];
            const float* fp = feat + (size_t)i * CIN + c * 8;
            f32x4 f0 = *(const f32x4*)fp;
            f32x4 f1 = *(const f32x4*)(fp + 4);
            o[0] = f2bf(f0.x * w); o[1] = f2bf(f0.y * w);
            o[2] = f2bf(f0.z * w); o[3] = f2bf(f0.w * w);
            o[4] = f2bf(f1.x * w); o[5] = f2bf(f1.y * w);
            o[6] = f2bf(f1.z * w); o[7] = f2bf(f1.w * w);
        }
        *(bf16x8*)(fb + (size_t)i * CIN + c * 8) = o;
    } else {
        int v = t - FB_ROWS * 4;
        if (v < CELLS * 4 * 64) {
            int l    = v & 63;
            int ct   = v >> 6;        // cell*4 + tt
            int tt   = ct & 3;
            int cell = ct >> 2;
            int fout = tt * 16 + (l & 15);
            int cin0 = (l >> 4) * 8;
            bf16x8 o;
#pragma unroll
            for (int j = 0; j < 8; ++j)
                o[j] = f2bf(W[cell * 2048 + (cin0 + j) * 64 + fout]);
            *(bf16x8*)(Wt2 + (size_t)v * 8) = o;
        }
    }
}

// One block = 128 threads = 2 waves = one 64-point group.
// Wave fhalf handles fout half; A-tile shared via LDS double buffer.
__global__ __launch_bounds__(128, 4) void conv64_kernel(
        const float* __restrict__ opos,
        const float* __restrict__ ipos,
        const int*   __restrict__ nbr,
        const unsigned short* __restrict__ Wt2,
        const unsigned short* __restrict__ fb,
        const float* __restrict__ bias,
        float* __restrict__ out) {
    __shared__ int s_idx[PPG][28];                       // [point][cell], pad 27->28
    __shared__ int s_vox[PPG];
    __shared__ __align__(16) unsigned char s_A[2][4 * 1056];  // [buf][chunk*1056 + row*16]

    const int tid   = threadIdx.x;
    const int lane  = tid & 63;
    const int fhalf = tid >> 6;
    const int m0    = blockIdx.x * PPG;

    const int vx0 = (int)ipos[0];
    const int vy0 = (int)ipos[1];
    const int vz0 = (int)ipos[2];

    if (fhalf == 0) {
        int m = m0 + lane;
        int vp = -1;
        if (m < M_OUT) {
            vp = ((int)opos[m * 3 + 0] + 1) |
                 (((int)opos[m * 3 + 1] + 1) << 8) |
                 (((int)opos[m * 3 + 2] + 1) << 16);
        }
        s_vox[lane] = vp;
    }
    __syncthreads();

    // stage 64x27 idx entries; invalid -> ZROW (zero feature row)
#pragma unroll
    for (int it = 0; it < 14; ++it) {
        int e = it * 128 + tid;
        if (e < CELLS * PPG) {
            int p = e / CELLS;
            int k = e - p * CELLS;
            int m = m0 + p;
            int id = (m < M_OUT) ? nbr[m * CELLS + k] : 0;
            int ox = k / 9, oy = (k / 3) % 3, oz = k % 3;   // off+1 in 0..2
            int tgt = (vx0 - ox + 2) | ((vy0 - oy + 2) << 8) | ((vz0 - oz + 2) << 16);
            bool valid = (id != 0) | (s_vox[p] == tgt);
            s_idx[p][k] = valid ? id : ZROW;
        }
    }
    __syncthreads();

    // staging roles: 4 contiguous lanes per 64B row -> 1 L1 request per row
    const int st_c  = lane & 3;
    const int st_r0 = fhalf * 32 + (lane >> 2);   // rows  0..31 (w0) / 32..63 (w1)
    const int st_r1 = st_r0 + 16;
    const unsigned short* fb_c = fb + st_c * 8;

    // reader roles (MFMA A fragment)
    const int g = lane >> 4;
    const int r = lane & 15;
    const int wbase = fhalf * 2;

    // prologue: stage cell 0 into buf 0; load B(0)
    {
        int i0 = s_idx[st_r0][0];
        int i1 = s_idx[st_r1][0];
        bf16x8 v0 = *(const bf16x8*)(fb_c + (size_t)i0 * CIN);
        bf16x8 v1 = *(const bf16x8*)(fb_c + (size_t)i1 * CIN);
        *(bf16x8*)&s_A[0][st_c * 1056 + st_r0 * 16] = v0;
        *(bf16x8*)&s_A[0][st_c * 1056 + st_r1 * 16] = v1;
    }
    bf16x8 cb0 = *(const bf16x8*)(Wt2 + (CELL_OF(0) * 4 + wbase + 0) * 512 + lane * 8);
    bf16x8 cb1 = *(const bf16x8*)(Wt2 + (CELL_OF(0) * 4 + wbase + 1) * 512 + lane * 8);
    __syncthreads();

    f32x4 acc[8];
#pragma unroll
    for (int i = 0; i < 8; ++i) acc[i] = (f32x4){0.f, 0.f, 0.f, 0.f};

#pragma unroll
    for (int k = 0; k < CELLS; ++k) {
        const int b = k & 1;
        bf16x8 v0, v1, nb0, nb1;
        const bool more = (k + 1 < CELLS);
        if (more) {
            int i0 = s_idx[st_r0][k + 1];
            int i1 = s_idx[st_r1][k + 1];
            v0 = *(const bf16x8*)(fb_c + (size_t)i0 * CIN);
            v1 = *(const bf16x8*)(fb_c + (size_t)i1 * CIN);
            const int c2 = CELL_OF(k + 1);
            nb0 = *(const bf16x8*)(Wt2 + (c2 * 4 + wbase + 0) * 512 + lane * 8);
            nb1 = *(const bf16x8*)(Wt2 + (c2 * 4 + wbase + 1) * 512 + lane * 8);
        }
        const unsigned char* Ab = &s_A[b][0];
        bf16x8 a0 = *(const bf16x8*)(Ab + g * 1056 +   0 + r * 16);
        bf16x8 a1 = *(const bf16x8*)(Ab + g * 1056 + 256 + r * 16);
        bf16x8 a2 = *(const bf16x8*)(Ab + g * 1056 + 512 + r * 16);
        bf16x8 a3 = *(const bf16x8*)(Ab + g * 1056 + 768 + r * 16);
        acc[0] = __builtin_amdgcn_mfma_f32_16x16x32_bf16(a0, cb0, acc[0], 0, 0, 0);
        acc[1] = __builtin_amdgcn_mfma_f32_16x16x32_bf16(a0, cb1, acc[1], 0, 0, 0);
        acc[2] = __builtin_amdgcn_mfma_f32_16x16x32_bf16(a1, cb0, acc[2], 0, 0, 0);
        acc[3] = __builtin_amdgcn_mfma_f32_16x16x32_bf16(a1, cb1, acc[3], 0, 0, 0);
        acc[4] = __builtin_amdgcn_mfma_f32_16x16x32_bf16(a2, cb0, acc[4], 0, 0, 0);
        acc[5] = __builtin_amdgcn_mfma_f32_16x16x32_bf16(a2, cb1, acc[5], 0, 0, 0);
        acc[6] = __builtin_amdgcn_mfma_f32_16x16x32_bf16(a3, cb0, acc[6], 0, 0, 0);
        acc[7] = __builtin_amdgcn_mfma_f32_16x16x32_bf16(a3, cb1, acc[7], 0, 0, 0);
        if (more) {
            *(bf16x8*)&s_A[b ^ 1][st_c * 1056 + st_r0 * 16] = v0;
            *(bf16x8*)&s_A[b ^ 1][st_c * 1056 + st_r1 * 16] = v1;
            cb0 = nb0;
            cb1 = nb1;
        }
        __syncthreads();
    }

    // D layout: col = lane&15 (fout within tile), row = (lane>>4)*4 + j (point)
    float bb0 = bias[fhalf * 32 + r];
    float bb1 = bias[fhalf * 32 + 16 + r];
#pragma unroll
    for (int h = 0; h < 4; ++h) {
        int base = m0 + h * 16 + 4 * g;
#pragma unroll
        for (int j = 0; j < 4; ++j) {
            int m = base + j;
            if (m < M_OUT) {
                float* op = out + (size_t)m * FOUT + fhalf * 32 + r;
                op[0]  = acc[h * 2 + 0][j] + bb0;
                op[16] = acc[h * 2 + 1][j] + bb1;
            }
        }
    }
}

extern "C" void kernel_launch(void* const* d_in, const int* in_sizes, int n_in,
                              void* d_out, int out_size, void* d_ws, size_t ws_size,
                              hipStream_t stream) {
    const float* feat = (const float*)d_in[0];
    const float* ipos = (const float*)d_in[1];
    const float* opos = (const float*)d_in[2];
    const float* imp  = (const float*)d_in[4];
    const float* W    = (const float*)d_in[5];
    const float* bias = (const float*)d_in[6];
    const int*   nbr  = (const int*)d_in[7];
    unsigned short* Wt2 = (unsigned short*)d_ws;
    unsigned short* fb  = (unsigned short*)((char*)d_ws + WT2_BYTES);
    float* out = (float*)d_out;

    int prep_threads = FB_ROWS * 4 + CELLS * 4 * 64;
    hipLaunchKernelGGL(prep_kernel, dim3((prep_threads + 255) / 256), dim3(256),
                       0, stream, W, feat, imp, Wt2, fb);
    hipLaunchKernelGGL(conv64_kernel, dim3(GROUPS), dim3(128), 0, stream,
                       opos, ipos, nbr, Wt2, fb, bias, out);
}

// Round 6
// 148.962 us; speedup vs baseline: 1.2558x; 1.0643x over previous
//
#include <hip/hip_runtime.h>
#include <hip/hip_bf16.h>

#define CELLS 27
#define CIN   32
#define FOUT  64
#define M_OUT 150000
#define N_INP 150000
#define GDIM  64
#define NVOX  (GDIM * GDIM * GDIM)          /* 262144 */

/* ---- dense-path workspace layout ---- */
#define GFEAT_SHORTS (NVOX * CIN)           /* 8388608 shorts = 16 MiB */
#define GFEAT_BYTES  (GFEAT_SHORTS * 2)
#define OUTMAP_BYTES (NVOX * 4)
#define WT2_SHORTS   (CELLS * 4 * 64 * 8)   /* 55296 */
#define WT2_BYTES    (WT2_SHORTS * 2)
#define DENSE_WS     ((size_t)GFEAT_BYTES + OUTMAP_BYTES + WT2_BYTES)

/* ---- fallback (R5) workspace layout ---- */
#define ZROW  N_INP
#define PPG   64
#define GROUPS ((M_OUT + PPG - 1) / PPG)
#define FB_ROWS  (N_INP + 1)
#define FB_BYTES (FB_ROWS * CIN * 2)

typedef __attribute__((ext_vector_type(4))) float f32x4;
typedef __attribute__((ext_vector_type(8))) short bf16x8;
typedef __attribute__((ext_vector_type(4))) int   i32x4;

__device__ __forceinline__ short f2bf(float x) {
    union { __hip_bfloat16 h; short s; } u;
    u.h = __float2bfloat16(x);
    return u.s;
}

/* ================= dense path ================= */

// zero gfeat (1048576 x 16B) and set outmap to -1 (65536 x 16B)
__global__ __launch_bounds__(256) void clear_kernel(unsigned short* __restrict__ gfeat,
                                                    int* __restrict__ outmap) {
    int t = blockIdx.x * 256 + threadIdx.x;
    if (t < 1048576) {
        ((i32x4*)gfeat)[t] = (i32x4){0, 0, 0, 0};
    } else {
        int u = t - 1048576;
        if (u < 65536) ((i32x4*)outmap)[u] = (i32x4){-1, -1, -1, -1};
    }
}

// scatter scaled features into dense grid; scatter outmap; build Wt2 fragment-major
__global__ __launch_bounds__(256) void build_kernel(const float* __restrict__ feat,
                                                    const float* __restrict__ ipos,
                                                    const float* __restrict__ opos,
                                                    const float* __restrict__ imp,
                                                    const float* __restrict__ W,
                                                    unsigned short* __restrict__ gfeat,
                                                    int* __restrict__ outmap,
                                                    unsigned short* __restrict__ Wt2) {
    int t = blockIdx.x * 256 + threadIdx.x;
    if (t < N_INP * 4) {
        int p = t >> 2, c = t & 3;
        int x = (int)ipos[p * 3 + 0];
        int y = (int)ipos[p * 3 + 1];
        int z = (int)ipos[p * 3 + 2];
        int flat = x + (y << 6) + (z << 12);
        float wv = imp[p];
        const float* fp = feat + (size_t)p * CIN + c * 8;
        f32x4 f0 = *(const f32x4*)fp;
        f32x4 f1 = *(const f32x4*)(fp + 4);
        bf16x8 o;
        o[0] = f2bf(f0.x * wv); o[1] = f2bf(f0.y * wv);
        o[2] = f2bf(f0.z * wv); o[3] = f2bf(f0.w * wv);
        o[4] = f2bf(f1.x * wv); o[5] = f2bf(f1.y * wv);
        o[6] = f2bf(f1.z * wv); o[7] = f2bf(f1.w * wv);
        *(bf16x8*)(gfeat + (size_t)flat * CIN + c * 8) = o;
    } else if (t < N_INP * 4 + M_OUT) {
        int m = t - N_INP * 4;
        int x = (int)opos[m * 3 + 0];
        int y = (int)opos[m * 3 + 1];
        int z = (int)opos[m * 3 + 2];
        outmap[x + (y << 6) + (z << 12)] = m;
    } else {
        int v = t - (N_INP * 4 + M_OUT);
        if (v < CELLS * 4 * 64) {
            int l    = v & 63;
            int ct   = v >> 6;
            int tt   = ct & 3;
            int cell = ct >> 2;
            int fout = tt * 16 + (l & 15);
            int cin0 = (l >> 4) * 8;
            bf16x8 o;
#pragma unroll
            for (int j = 0; j < 8; ++j)
                o[j] = f2bf(W[cell * 2048 + (cin0 + j) * 64 + fout]);
            *(bf16x8*)(Wt2 + (size_t)v * 8) = o;
        }
    }
}

// 8x8x4 tile per 256-thread block (4 waves x one z-slice of 64 outputs).
// Halo 10x10x6 voxels, 80B LDS stride (2-way-free ds_read_b128). No barriers
// in the 27-cell loop; B prefetched one cell ahead from fragment-major Wt2.
__global__ __launch_bounds__(256, 2) void conv_dense_kernel(
        const unsigned short* __restrict__ gfeat,
        const int*   __restrict__ outmap,
        const unsigned short* __restrict__ Wt2,
        const float* __restrict__ bias,
        float* __restrict__ out) {
    __shared__ __align__(16) unsigned char sh[48000];   /* 600 voxels * 80B */

    const int tid = threadIdx.x;
    const int bid = blockIdx.x;
    const int bx0 = (bid & 7) * 8;
    const int by0 = ((bid >> 3) & 7) * 8;
    const int bz0 = (bid >> 6) * 4;

    /* halo load: 2400 16B-chunks, coalesced along x */
#pragma unroll
    for (int it = 0; it < 10; ++it) {
        int c = it * 256 + tid;
        if (c < 2400) {
            int v = c >> 2, ch = c & 3;
            int q10  = (v * 6554) >> 16;      /* v/10   (v<600)  */
            int hx   = v - q10 * 10;
            int q100 = (q10 * 6554) >> 16;    /* q10/10 (q10<60) */
            int hy   = q10 - q100 * 10;
            int hz   = q100;
            int gx = bx0 - 1 + hx, gy = by0 - 1 + hy, gz = bz0 - 1 + hz;
            bf16x8 val = {0, 0, 0, 0, 0, 0, 0, 0};
            if (((unsigned)gx < 64u) & ((unsigned)gy < 64u) & ((unsigned)gz < 64u)) {
                int flat = gx + (gy << 6) + (gz << 12);
                val = *(const bf16x8*)(gfeat + (size_t)flat * CIN + ch * 8);
            }
            *(bf16x8*)&sh[v * 80 + ch * 16] = val;
        }
    }
    __syncthreads();

    const int w    = tid >> 6;      /* wave = z-slice within tile */
    const int lane = tid & 63;
    const int r = lane & 15;        /* A row / B fout-in-tile / D col */
    const int g = lane >> 4;        /* cin chunk / D row group */

    const unsigned char* Ab = sh + (r & 7) * 80 + (r >> 3) * 800 + w * 8000 + g * 16;
    const unsigned short* Bp = Wt2 + lane * 8;

    f32x4 acc[4][4];
#pragma unroll
    for (int mt = 0; mt < 4; ++mt)
#pragma unroll
        for (int nt = 0; nt < 4; ++nt) acc[mt][nt] = (f32x4){0.f, 0.f, 0.f, 0.f};

    bf16x8 bb[2][4];
#pragma unroll
    for (int nt = 0; nt < 4; ++nt)
        bb[0][nt] = *(const bf16x8*)(Bp + nt * 512);

#pragma unroll
    for (int cell = 0; cell < CELLS; ++cell) {
        const int cur = cell & 1, nxt = cur ^ 1;
        const int hx = cell % 3, hy = (cell / 3) % 3, hz = cell / 9;
        if (cell + 1 < CELLS) {
#pragma unroll
            for (int nt = 0; nt < 4; ++nt)
                bb[nxt][nt] = *(const bf16x8*)(Bp + (cell + 1) * 2048 + nt * 512);
        }
#pragma unroll
        for (int mt = 0; mt < 4; ++mt) {
            bf16x8 a = *(const bf16x8*)(Ab + hz * 8000 + (hy + 2 * mt) * 800 + hx * 80);
#pragma unroll
            for (int nt = 0; nt < 4; ++nt)
                acc[mt][nt] = __builtin_amdgcn_mfma_f32_16x16x32_bf16(a, bb[cur][nt],
                                                                      acc[mt][nt], 0, 0, 0);
        }
    }

    /* epilogue: D col = lane&15, row = g*4+j; write only real outputs */
    float bv0 = bias[r], bv1 = bias[16 + r], bv2 = bias[32 + r], bv3 = bias[48 + r];
    const int obase = bx0 + (by0 << 6) + ((bz0 + w) << 12);
#pragma unroll
    for (int mt = 0; mt < 4; ++mt) {
#pragma unroll
        for (int j = 0; j < 4; ++j) {
            int row = mt * 16 + g * 4 + j;
            int om = outmap[obase + (row & 7) + ((row >> 3) << 6)];
            if (om >= 0) {
                float* op = out + (size_t)om * FOUT + r;
                op[0]  = acc[mt][0][j] + bv0;
                op[16] = acc[mt][1][j] + bv1;
                op[32] = acc[mt][2][j] + bv2;
                op[48] = acc[mt][3][j] + bv3;
            }
        }
    }
}

/* ================= fallback path (R5, proven) ================= */

#define CELL_OF(k) (((k) % 3) * 9 + (((k) / 3) % 3) * 3 + ((k) / 9))

__global__ __launch_bounds__(256) void prep_fb_kernel(const float* __restrict__ W,
                                                      const float* __restrict__ feat,
                                                      const float* __restrict__ imp,
                                                      unsigned short* __restrict__ Wt2,
                                                      unsigned short* __restrict__ fb) {
    int t = blockIdx.x * 256 + threadIdx.x;
    if (t < FB_ROWS * 4) {
        int i = t >> 2, c = t & 3;
        bf16x8 o = {0, 0, 0, 0, 0, 0, 0, 0};
        if (i < N_INP) {
            float w = imp[i];
            const float* fp = feat + (size_t)i * CIN + c * 8;
            f32x4 f0 = *(const f32x4*)fp;
            f32x4 f1 = *(const f32x4*)(fp + 4);
            o[0] = f2bf(f0.x * w); o[1] = f2bf(f0.y * w);
            o[2] = f2bf(f0.z * w); o[3] = f2bf(f0.w * w);
            o[4] = f2bf(f1.x * w); o[5] = f2bf(f1.y * w);
            o[6] = f2bf(f1.z * w); o[7] = f2bf(f1.w * w);
        }
        *(bf16x8*)(fb + (size_t)i * CIN + c * 8) = o;
    } else {
        int v = t - FB_ROWS * 4;
        if (v < CELLS * 4 * 64) {
            int l    = v & 63;
            int ct   = v >> 6;
            int tt   = ct & 3;
            int cell = ct >> 2;
            int fout = tt * 16 + (l & 15);
            int cin0 = (l >> 4) * 8;
            bf16x8 o;
#pragma unroll
            for (int j = 0; j < 8; ++j)
                o[j] = f2bf(W[cell * 2048 + (cin0 + j) * 64 + fout]);
            *(bf16x8*)(Wt2 + (size_t)v * 8) = o;
        }
    }
}

__global__ __launch_bounds__(128, 4) void conv64_kernel(
        const float* __restrict__ opos,
        const float* __restrict__ ipos,
        const int*   __restrict__ nbr,
        const unsigned short* __restrict__ Wt2,
        const unsigned short* __restrict__ fb,
        const float* __restrict__ bias,
        float* __restrict__ out) {
    __shared__ int s_idx[PPG][28];
    __shared__ int s_vox[PPG];
    __shared__ __align__(16) unsigned char s_A[2][4 * 1056];

    const int tid   = threadIdx.x;
    const int lane  = tid & 63;
    const int fhalf = tid >> 6;
    const int m0    = blockIdx.x * PPG;

    const int vx0 = (int)ipos[0];
    const int vy0 = (int)ipos[1];
    const int vz0 = (int)ipos[2];

    if (fhalf == 0) {
        int m = m0 + lane;
        int vp = -1;
        if (m < M_OUT) {
            vp = ((int)opos[m * 3 + 0] + 1) |
                 (((int)opos[m * 3 + 1] + 1) << 8) |
                 (((int)opos[m * 3 + 2] + 1) << 16);
        }
        s_vox[lane] = vp;
    }
    __syncthreads();

#pragma unroll
    for (int it = 0; it < 14; ++it) {
        int e = it * 128 + tid;
        if (e < CELLS * PPG) {
            int p = e / CELLS;
            int k = e - p * CELLS;
            int m = m0 + p;
            int id = (m < M_OUT) ? nbr[m * CELLS + k] : 0;
            int ox = k / 9, oy = (k / 3) % 3, oz = k % 3;
            int tgt = (vx0 - ox + 2) | ((vy0 - oy + 2) << 8) | ((vz0 - oz + 2) << 16);
            bool valid = (id != 0) | (s_vox[p] == tgt);
            s_idx[p][k] = valid ? id : ZROW;
        }
    }
    __syncthreads();

    const int st_c  = lane & 3;
    const int st_r0 = fhalf * 32 + (lane >> 2);
    const int st_r1 = st_r0 + 16;
    const unsigned short* fb_c = fb + st_c * 8;

    const int g = lane >> 4;
    const int r = lane & 15;
    const int wbase = fhalf * 2;

    {
        int i0 = s_idx[st_r0][0];
        int i1 = s_idx[st_r1][0];
        bf16x8 v0 = *(const bf16x8*)(fb_c + (size_t)i0 * CIN);
        bf16x8 v1 = *(const bf16x8*)(fb_c + (size_t)i1 * CIN);
        *(bf16x8*)&s_A[0][st_c * 1056 + st_r0 * 16] = v0;
        *(bf16x8*)&s_A[0][st_c * 1056 + st_r1 * 16] = v1;
    }
    bf16x8 cb0 = *(const bf16x8*)(Wt2 + (CELL_OF(0) * 4 + wbase + 0) * 512 + lane * 8);
    bf16x8 cb1 = *(const bf16x8*)(Wt2 + (CELL_OF(0) * 4 + wbase + 1) * 512 + lane * 8);
    __syncthreads();

    f32x4 acc[8];
#pragma unroll
    for (int i = 0; i < 8; ++i) acc[i] = (f32x4){0.f, 0.f, 0.f, 0.f};

#pragma unroll
    for (int k = 0; k < CELLS; ++k) {
        const int b = k & 1;
        bf16x8 v0, v1, nb0, nb1;
        const bool more = (k + 1 < CELLS);
        if (more) {
            int i0 = s_idx[st_r0][k + 1];
            int i1 = s_idx[st_r1][k + 1];
            v0 = *(const bf16x8*)(fb_c + (size_t)i0 * CIN);
            v1 = *(const bf16x8*)(fb_c + (size_t)i1 * CIN);
            const int c2 = CELL_OF(k + 1);
            nb0 = *(const bf16x8*)(Wt2 + (c2 * 4 + wbase + 0) * 512 + lane * 8);
            nb1 = *(const bf16x8*)(Wt2 + (c2 * 4 + wbase + 1) * 512 + lane * 8);
        }
        const unsigned char* Ab = &s_A[b][0];
        bf16x8 a0 = *(const bf16x8*)(Ab + g * 1056 +   0 + r * 16);
        bf16x8 a1 = *(const bf16x8*)(Ab + g * 1056 + 256 + r * 16);
        bf16x8 a2 = *(const bf16x8*)(Ab + g * 1056 + 512 + r * 16);
        bf16x8 a3 = *(const bf16x8*)(Ab + g * 1056 + 768 + r * 16);
        acc[0] = __builtin_amdgcn_mfma_f32_16x16x32_bf16(a0, cb0, acc[0], 0, 0, 0);
        acc[1] = __builtin_amdgcn_mfma_f32_16x16x32_bf16(a0, cb1, acc[1], 0, 0, 0);
        acc[2] = __builtin_amdgcn_mfma_f32_16x16x32_bf16(a1, cb0, acc[2], 0, 0, 0);
        acc[3] = __builtin_amdgcn_mfma_f32_16x16x32_bf16(a1, cb1, acc[3], 0, 0, 0);
        acc[4] = __builtin_amdgcn_mfma_f32_16x16x32_bf16(a2, cb0, acc[4], 0, 0, 0);
        acc[5] = __builtin_amdgcn_mfma_f32_16x16x32_bf16(a2, cb1, acc[5], 0, 0, 0);
        acc[6] = __builtin_amdgcn_mfma_f32_16x16x32_bf16(a3, cb0, acc[6], 0, 0, 0);
        acc[7] = __builtin_amdgcn_mfma_f32_16x16x32_bf16(a3, cb1, acc[7], 0, 0, 0);
        if (more) {
            *(bf16x8*)&s_A[b ^ 1][st_c * 1056 + st_r0 * 16] = v0;
            *(bf16x8*)&s_A[b ^ 1][st_c * 1056 + st_r1 * 16] = v1;
            cb0 = nb0;
            cb1 = nb1;
        }
        __syncthreads();
    }

    float bb0 = bias[fhalf * 32 + r];
    float bb1 = bias[fhalf * 32 + 16 + r];
#pragma unroll
    for (int h = 0; h < 4; ++h) {
        int base = m0 + h * 16 + 4 * g;
#pragma unroll
        for (int j = 0; j < 4; ++j) {
            int m = base + j;
            if (m < M_OUT) {
                float* op = out + (size_t)m * FOUT + fhalf * 32 + r;
                op[0]  = acc[h * 2 + 0][j] + bb0;
                op[16] = acc[h * 2 + 1][j] + bb1;
            }
        }
    }
}

/* ================= launch ================= */

extern "C" void kernel_launch(void* const* d_in, const int* in_sizes, int n_in,
                              void* d_out, int out_size, void* d_ws, size_t ws_size,
                              hipStream_t stream) {
    const float* feat = (const float*)d_in[0];
    const float* ipos = (const float*)d_in[1];
    const float* opos = (const float*)d_in[2];
    const float* imp  = (const float*)d_in[4];
    const float* W    = (const float*)d_in[5];
    const float* bias = (const float*)d_in[6];
    const int*   nbr  = (const int*)d_in[7];
    float* out = (float*)d_out;

    if (ws_size >= DENSE_WS) {
        unsigned short* gfeat = (unsigned short*)d_ws;
        int* outmap = (int*)((char*)d_ws + GFEAT_BYTES);
        unsigned short* Wt2 = (unsigned short*)((char*)d_ws + GFEAT_BYTES + OUTMAP_BYTES);

        hipLaunchKernelGGL(clear_kernel, dim3((1048576 + 65536 + 255) / 256), dim3(256),
                           0, stream, gfeat, outmap);
        int build_threads = N_INP * 4 + M_OUT + CELLS * 4 * 64;
        hipLaunchKernelGGL(build_kernel, dim3((build_threads + 255) / 256), dim3(256),
                           0, stream, feat, ipos, opos, imp, W, gfeat, outmap, Wt2);
        hipLaunchKernelGGL(conv_dense_kernel, dim3(1024), dim3(256), 0, stream,
                           gfeat, outmap, Wt2, bias, out);
    } else {
        unsigned short* Wt2 = (unsigned short*)d_ws;
        unsigned short* fb  = (unsigned short*)((char*)d_ws + WT2_BYTES);
        int prep_threads = FB_ROWS * 4 + CELLS * 4 * 64;
        hipLaunchKernelGGL(prep_fb_kernel, dim3((prep_threads + 255) / 256), dim3(256),
                           0, stream, W, feat, imp, Wt2, fb);
        hipLaunchKernelGGL(conv64_kernel, dim3(GROUPS), dim3(128), 0, stream,
                           opos, ipos, nbr, Wt2, fb, bias, out);
    }
}